// Round 4
// baseline (289.853 us; speedup 1.0000x reference)
//
#include <hip/hip_runtime.h>
#include <hip/hip_bf16.h>
#include <math.h>

#define EPSF 1e-12f

typedef __attribute__((ext_vector_type(8))) short bf16x8;
typedef __attribute__((ext_vector_type(4))) float f32x4;
typedef __attribute__((ext_vector_type(4))) short short4v;
typedef __attribute__((ext_vector_type(4))) unsigned short ushort4v;

static __device__ __forceinline__ short f2bf(float f) {
  union { __hip_bfloat16 h; short s; } u;
  u.h = __float2bfloat16(f);
  return u.s;
}

// K2: logits = (w @ x) * invn[s] via bf16 MFMA; fused per-s L2-norm;
// softmax over k; writes a' = a*invn (bf16) and suma (fp32 atomics).
// Block: one (n, 64-s tile). w frags live in registers (loaded once).
// x staged bf16 [c][s] then LDS-transposed to xt[s][c] so the B-frag is a
// single ds_read_b128 (was 8 scalar ds_read_b32 + 8 cvt per MFMA).
__global__ __launch_bounds__(256) void k2_mfma(
    const float* __restrict__ x, const float* __restrict__ w,
    unsigned short* __restrict__ ap, float* __restrict__ suma) {
  __shared__ __align__(16) short xb[64][72];   // [c_local][s_local] bf16
  __shared__ __align__(16) short xt[64][72];   // [s_local][c_local] bf16
  __shared__ __align__(16) float red[4][64];   // per-wave reduction scratch
  __shared__ float invs[64];
  __shared__ float gmaxs[64];
  __shared__ float gsums[64];

  const int n = blockIdx.y;
  const int s0 = blockIdx.x << 6;
  const int t = threadIdx.x;
  const int lane = t & 63;
  const int wid = t >> 6;        // wave id = k-band
  const int col = t & 15;        // MFMA col (s) / frag row
  const int quad = (t >> 4) & 3; // MFMA quad
  const int cr = t >> 4;         // staging row 0..15
  const int sg = t & 15;         // staging float4 col

  // ---- preload w fragments: wf[f] covers c = 32f + 8*quad + j, k = 16*wid+col
  bf16x8 wf[16];
#pragma unroll
  for (int f = 0; f < 16; ++f) {
    const float* wp = &w[(size_t)(((wid << 4) + col) << 9) + (f << 5) + (quad << 3)];
    float4 l0 = *(const float4*)wp;
    float4 l1 = *(const float4*)(wp + 4);
    wf[f][0] = f2bf(l0.x); wf[f][1] = f2bf(l0.y);
    wf[f][2] = f2bf(l0.z); wf[f][3] = f2bf(l0.w);
    wf[f][4] = f2bf(l1.x); wf[f][5] = f2bf(l1.y);
    wf[f][6] = f2bf(l1.z); wf[f][7] = f2bf(l1.w);
  }

  f32x4 acc[4] = {{0,0,0,0},{0,0,0,0},{0,0,0,0},{0,0,0,0}};
  float ssq0 = 0.f, ssq1 = 0.f, ssq2 = 0.f, ssq3 = 0.f;

#pragma unroll
  for (int c0 = 0; c0 < 512; c0 += 64) {
    // phase 1: global -> xb[c][s] bf16 (+ ssq on raw fp32)
#pragma unroll
    for (int p = 0; p < 4; ++p) {
      int c = cr + (p << 4);
      float4 g = *(const float4*)&x[((size_t)((n << 9) + c0 + c) << 10) + s0 + (sg << 2)];
      ssq0 = fmaf(g.x, g.x, ssq0); ssq1 = fmaf(g.y, g.y, ssq1);
      ssq2 = fmaf(g.z, g.z, ssq2); ssq3 = fmaf(g.w, g.w, ssq3);
      short4v h; h.x = f2bf(g.x); h.y = f2bf(g.y); h.z = f2bf(g.z); h.w = f2bf(g.w);
      *(short4v*)&xb[c][sg << 2] = h;
    }
    __syncthreads();
    // phase 2: LDS transpose xb[c][s] -> xt[s][c]
    //   read: lane l takes row c=l, octet g (b128); write: 8 u16 along xt row
    //   (64 lanes -> 32 consecutive dwords, 2 lanes/dword = 2-way = free)
#pragma unroll
    for (int i = 0; i < 2; ++i) {
      int g = (wid << 1) + i;
      bf16x8 v = *(const bf16x8*)&xb[lane][g << 3];
#pragma unroll
      for (int j = 0; j < 8; ++j) xt[(g << 3) + j][lane] = v[j];
    }
    __syncthreads();
    // phase 3: MFMA. B-frag = one ds_read_b128 from xt.
#pragma unroll
    for (int cc = 0; cc < 64; cc += 32) {
      bf16x8 af = wf[(c0 >> 5) + (cc >> 5)];
#pragma unroll
      for (int sgr = 0; sgr < 4; ++sgr) {
        bf16x8 bfr = *(const bf16x8*)&xt[(sgr << 4) + col][cc + (quad << 3)];
        acc[sgr] = __builtin_amdgcn_mfma_f32_16x16x32_bf16(af, bfr, acc[sgr], 0, 0, 0);
      }
    }
    __syncthreads();
  }

  // ---- per-s inverse norm (thread's 4 s fixed = 4sg..4sg+3) ----
  ssq0 += __shfl_xor(ssq0, 16, 64); ssq0 += __shfl_xor(ssq0, 32, 64);
  ssq1 += __shfl_xor(ssq1, 16, 64); ssq1 += __shfl_xor(ssq1, 32, 64);
  ssq2 += __shfl_xor(ssq2, 16, 64); ssq2 += __shfl_xor(ssq2, 32, 64);
  ssq3 += __shfl_xor(ssq3, 16, 64); ssq3 += __shfl_xor(ssq3, 32, 64);
  if (lane < 16) {
    float4 v; v.x = ssq0; v.y = ssq1; v.z = ssq2; v.w = ssq3;
    *(float4*)&red[wid][sg << 2] = v;
  }
  __syncthreads();
  if (t < 64) {
    float tot = red[0][t] + red[1][t] + red[2][t] + red[3][t];
    invs[t] = 1.0f / fmaxf(sqrtf(tot), EPSF);
  }
  __syncthreads();

  // ---- softmax over k for each s ----
  float li[4];
#pragma unroll
  for (int sgr = 0; sgr < 4; ++sgr) li[sgr] = invs[(sgr << 4) + col];
  float le[4][4];
#pragma unroll
  for (int sgr = 0; sgr < 4; ++sgr)
#pragma unroll
    for (int r = 0; r < 4; ++r) le[sgr][r] = acc[sgr][r] * li[sgr];

  float mx[4];
#pragma unroll
  for (int sgr = 0; sgr < 4; ++sgr) {
    float m = fmaxf(fmaxf(le[sgr][0], le[sgr][1]), fmaxf(le[sgr][2], le[sgr][3]));
    m = fmaxf(m, __shfl_xor(m, 16, 64));
    m = fmaxf(m, __shfl_xor(m, 32, 64));
    mx[sgr] = m;
  }
  if (lane < 16) {
#pragma unroll
    for (int sgr = 0; sgr < 4; ++sgr) red[wid][(sgr << 4) + sg] = mx[sgr];
  }
  __syncthreads();
  if (t < 64)
    gmaxs[t] = fmaxf(fmaxf(red[0][t], red[1][t]), fmaxf(red[2][t], red[3][t]));
  __syncthreads();

  float ps[4];
#pragma unroll
  for (int sgr = 0; sgr < 4; ++sgr) {
    float gm = gmaxs[(sgr << 4) + col];
    float p = 0.f;
#pragma unroll
    for (int r = 0; r < 4; ++r) {
      float e = __expf(le[sgr][r] - gm);
      le[sgr][r] = e;
      p += e;
    }
    p += __shfl_xor(p, 16, 64);
    p += __shfl_xor(p, 32, 64);
    ps[sgr] = p;
  }
  if (lane < 16) {
#pragma unroll
    for (int sgr = 0; sgr < 4; ++sgr) red[wid][(sgr << 4) + sg] = ps[sgr];
  }
  __syncthreads();
  if (t < 64) gsums[t] = red[0][t] + red[1][t] + red[2][t] + red[3][t];
  __syncthreads();

  // ---- a, a' = a*invn, suma ----
  float sk[4] = {0.f, 0.f, 0.f, 0.f};
#pragma unroll
  for (int sgr = 0; sgr < 4; ++sgr) {
    float rinv = 1.0f / gsums[(sgr << 4) + col];
#pragma unroll
    for (int r = 0; r < 4; ++r) {
      float av = le[sgr][r] * rinv;            // a
      sk[r] += av;
      float apv = av * li[sgr];                // a' = a*invn[s]
      int k = (wid << 4) + (quad << 2) + r;
      ap[((size_t)((n << 6) + k) << 10) + s0 + (sgr << 4) + col] =
          (unsigned short)f2bf(apv);
    }
  }
#pragma unroll
  for (int r = 0; r < 4; ++r) {
    sk[r] += __shfl_xor(sk[r], 1, 64);
    sk[r] += __shfl_xor(sk[r], 2, 64);
    sk[r] += __shfl_xor(sk[r], 4, 64);
    sk[r] += __shfl_xor(sk[r], 8, 64);
  }
  if (col == 0) {
#pragma unroll
    for (int r = 0; r < 4; ++r)
      atomicAdd(&suma[(n << 6) + (wid << 4) + (quad << 2) + r], sk[r]);
  }
}

// K3: vlad^T[c,k] = sum_s x[c,s]*a'[k,s]  (bf16 MFMA, x as A, a' as B),
// then - suma[k]*cent[k,c], rnorm2 atomics, LDS-transposed coalesced store.
__global__ __launch_bounds__(256) void k3_mfma(
    const float* __restrict__ x, const unsigned short* __restrict__ ap,
    const float* __restrict__ cent, const float* __restrict__ suma,
    float* __restrict__ out, float* __restrict__ rnorm2) {
  __shared__ __align__(16) char sm[64 * 72 * 2 * 2];  // 18432 B
  short (*xb)[72] = reinterpret_cast<short(*)[72]>(sm);          // [c][s] bf16
  short (*at)[72] = reinterpret_cast<short(*)[72]>(sm + 9216);   // [k][s] bf16
  float (*lt)[68] = reinterpret_cast<float(*)[68]>(sm);          // [k][c] (epilogue)

  const int n = blockIdx.y;
  const int c0 = blockIdx.x << 6;
  const int t = threadIdx.x;
  const int lane = t & 63;
  const int wid = t >> 6;        // c-band
  const int col = t & 15;
  const int quad = (t >> 4) & 3;
  const int cr = t >> 4;
  const int sg = t & 15;

  f32x4 acc[4] = {{0,0,0,0},{0,0,0,0},{0,0,0,0},{0,0,0,0}};

  for (int s0 = 0; s0 < 1024; s0 += 64) {
#pragma unroll
    for (int p = 0; p < 4; ++p) {
      int c = cr + (p << 4);
      float4 g = *(const float4*)&x[((size_t)((n << 9) + c0 + c) << 10) + s0 + (sg << 2)];
      short4v hx; hx.x = f2bf(g.x); hx.y = f2bf(g.y); hx.z = f2bf(g.z); hx.w = f2bf(g.w);
      *(short4v*)&xb[c][sg << 2] = hx;
      ushort4v a4 = *(const ushort4v*)&ap[((size_t)((n << 6) + c) << 10) + s0 + (sg << 2)];
      *(ushort4v*)&at[c][sg << 2] = a4;
    }
    __syncthreads();
#pragma unroll
    for (int ss = 0; ss < 64; ss += 32) {
      bf16x8 af = *(const bf16x8*)&xb[(wid << 4) + col][ss + (quad << 3)];
#pragma unroll
      for (int kt = 0; kt < 4; ++kt) {
        bf16x8 bfr = *(const bf16x8*)&at[(kt << 4) + col][ss + (quad << 3)];
        acc[kt] = __builtin_amdgcn_mfma_f32_16x16x32_bf16(af, bfr, acc[kt], 0, 0, 0);
      }
    }
    __syncthreads();
  }

  // epilogue: lane holds D[c = wid*16+quad*4+r][k = kt*16+col]
  float sa[4];
#pragma unroll
  for (int kt = 0; kt < 4; ++kt) sa[kt] = suma[(n << 6) + (kt << 4) + col];
  const int crow = (wid << 4) + (quad << 2);
  float r2[4] = {0.f, 0.f, 0.f, 0.f};
#pragma unroll
  for (int kt = 0; kt < 4; ++kt) {
    int k = (kt << 4) + col;
#pragma unroll
    for (int r = 0; r < 4; ++r) {
      int c = crow + r;
      float ce = cent[(k << 9) + c0 + c];
      float val = acc[kt][r] - sa[kt] * ce;
      r2[kt] = fmaf(val, val, r2[kt]);
      lt[k][c] = val;
    }
  }
#pragma unroll
  for (int kt = 0; kt < 4; ++kt) {
    r2[kt] += __shfl_xor(r2[kt], 16, 64);
    r2[kt] += __shfl_xor(r2[kt], 32, 64);
  }
  if (lane < 16) {
#pragma unroll
    for (int kt = 0; kt < 4; ++kt)
      atomicAdd(&rnorm2[(n << 6) + (kt << 4) + sg], r2[kt]);
  }
  __syncthreads();
  // coalesced store of the 64k x 64c tile
#pragma unroll
  for (int u = 0; u < 4; ++u) {
    int k = t >> 2;
    int c = ((t & 3) << 2) + (u << 4);
    float4 v = *(const float4*)&lt[k][c];
    *(float4*)&out[((size_t)((n << 6) + k) << 9) + c0 + c] = v;
  }
}

// K4: fac[n,k] = intra-norm factor * global-norm factor
__global__ __launch_bounds__(64) void k4_factors(const float* __restrict__ rnorm2,
                                                 float* __restrict__ fac) {
  int n = blockIdx.x, k = threadIdx.x;
  float r2 = rnorm2[(n << 6) + k];
  float rn = sqrtf(r2);
  float f = 1.0f / fmaxf(rn, EPSF);
  float nr = rn * f;
  float g = nr * nr;
#pragma unroll
  for (int off = 32; off > 0; off >>= 1) g += __shfl_xor(g, off, 64);
  fac[(n << 6) + k] = f * (1.0f / fmaxf(sqrtf(g), EPSF));
}

// K5: out *= fac  (in place; d_out fully rewritten by K3 each call)
__global__ __launch_bounds__(256) void k5_scale(const float* __restrict__ vlad,
                                                const float* __restrict__ fac,
                                                float* __restrict__ out) {
  int idx = blockIdx.x * 256 + threadIdx.x;  // float4 index
  float4 v = ((const float4*)vlad)[idx];
  float f = fac[idx >> 7];
  float4 o;
  o.x = v.x * f; o.y = v.y * f; o.z = v.z * f; o.w = v.w * f;
  ((float4*)out)[idx] = o;
}

extern "C" void kernel_launch(void* const* d_in, const int* in_sizes, int n_in,
                              void* d_out, int out_size, void* d_ws, size_t ws_size,
                              hipStream_t stream) {
  (void)in_sizes; (void)n_in; (void)out_size; (void)ws_size;
  const float* x = (const float*)d_in[0];     // (64,512,32,32)
  const float* w = (const float*)d_in[1];     // (64,512)
  const float* cent = (const float*)d_in[2];  // (64,512)
  float* out = (float*)d_out;                 // (64, 64*512)

  float* ws = (float*)d_ws;
  float* suma = ws;                                   // 4096
  float* rnorm2 = ws + 4096;                          // 4096
  float* fac = ws + 8192;                             // 4096
  unsigned short* ap = (unsigned short*)(ws + 12288); // 64*64*1024 bf16 = 8 MB

  hipMemsetAsync(ws, 0, 8192 * sizeof(float), stream);  // suma + rnorm2
  k2_mfma<<<dim3(16, 64), 256, 0, stream>>>(x, w, ap, suma);
  k3_mfma<<<dim3(8, 64), 256, 0, stream>>>(x, ap, cent, suma, out, rnorm2);
  k4_factors<<<64, 64, 0, stream>>>(rnorm2, fac);
  k5_scale<<<2048, 256, 0, stream>>>(out, fac, out);
}

// Round 5
// 254.666 us; speedup vs baseline: 1.1382x; 1.1382x over previous
//
#include <hip/hip_runtime.h>
#include <hip/hip_bf16.h>
#include <math.h>

#define EPSF 1e-12f

typedef __attribute__((ext_vector_type(8))) short bf16x8;
typedef __attribute__((ext_vector_type(4))) float f32x4;
typedef __attribute__((ext_vector_type(4))) short short4v;
typedef __attribute__((ext_vector_type(4))) unsigned short ushort4v;

static __device__ __forceinline__ short f2bf(float f) {
  union { __hip_bfloat16 h; short s; } u;
  u.h = __float2bfloat16(f);
  return u.s;
}

// K2: logits = (w @ x) * invn[s]  via bf16 MFMA; fused per-s L2-norm;
// softmax over k; writes a' = a*invn (bf16) and suma (fp32 atomics).
// Block: one (n, 64-s tile). 4 waves, wave w owns k-rows [16w,16w+16).
// xf pitch 70: gather bank = (70*(cb+j)+col)%32 = (6(cb+j)+col)%32; the 8 j's
// hit 8 distinct banks and quads alias only 2-way (free, m136).
// NOTE (R4 post-mortem): replacing this gather with an in-LDS transpose
// regressed k2 35->92 us (3rd barrier/tile + 8-way-conflicted transpose
// reads + scalar b16 writes serialize at ~2 blocks/CU). Keep the gather.
__global__ __launch_bounds__(256) void k2_mfma(
    const float* __restrict__ x, const float* __restrict__ w,
    unsigned short* __restrict__ ap, float* __restrict__ suma) {
  __shared__ __align__(16) float xf[64][70];   // [c_local][s_local] fp32
  __shared__ __align__(16) short wb[64][72];   // [k][c_local] bf16
  __shared__ __align__(16) float red[4][64];   // per-wave reduction scratch
  __shared__ float invs[64];
  __shared__ float gmaxs[64];
  __shared__ float gsums[64];

  const int n = blockIdx.y;
  const int s0 = blockIdx.x << 6;
  const int t = threadIdx.x;
  const int lane = t & 63;
  const int wid = t >> 6;        // wave id = k-band
  const int col = t & 15;        // MFMA col (s) / frag row
  const int quad = (t >> 4) & 3; // MFMA quad
  const int cr = t >> 4;         // staging row 0..15
  const int sg = t & 15;         // staging float4 col

  f32x4 acc[4] = {{0,0,0,0},{0,0,0,0},{0,0,0,0},{0,0,0,0}};
  float ssq0 = 0.f, ssq1 = 0.f, ssq2 = 0.f, ssq3 = 0.f;

  for (int c0 = 0; c0 < 512; c0 += 64) {
#pragma unroll
    for (int p = 0; p < 4; ++p) {
      int c = cr + (p << 4);
      float4 g = *(const float4*)&x[((size_t)((n << 9) + c0 + c) << 10) + s0 + (sg << 2)];
      float2 glo; glo.x = g.x; glo.y = g.y;
      float2 ghi; ghi.x = g.z; ghi.y = g.w;
      *(float2*)&xf[c][sg << 2] = glo;
      *(float2*)&xf[c][(sg << 2) + 2] = ghi;
      ssq0 = fmaf(g.x, g.x, ssq0); ssq1 = fmaf(g.y, g.y, ssq1);
      ssq2 = fmaf(g.z, g.z, ssq2); ssq3 = fmaf(g.w, g.w, ssq3);
      float4 gw = *(const float4*)&w[(c << 9) + c0 + (sg << 2)];  // w[k=c][c0+4sg]
      short4v hw; hw.x = f2bf(gw.x); hw.y = f2bf(gw.y); hw.z = f2bf(gw.z); hw.w = f2bf(gw.w);
      *(short4v*)&wb[c][sg << 2] = hw;
    }
    __syncthreads();
#pragma unroll
    for (int cc = 0; cc < 64; cc += 32) {
      bf16x8 af = *(const bf16x8*)&wb[(wid << 4) + col][cc + (quad << 3)];
      int cb = cc + (quad << 3);
#pragma unroll
      for (int sgr = 0; sgr < 4; ++sgr) {
        int sc = (sgr << 4) + col;
        bf16x8 bfr;
#pragma unroll
        for (int j = 0; j < 8; ++j) bfr[j] = f2bf(xf[cb + j][sc]);  // 2-way (free)
        acc[sgr] = __builtin_amdgcn_mfma_f32_16x16x32_bf16(af, bfr, acc[sgr], 0, 0, 0);
      }
    }
    __syncthreads();
  }

  // ---- per-s inverse norm (thread's 4 s fixed = 4sg..4sg+3) ----
  ssq0 += __shfl_xor(ssq0, 16, 64); ssq0 += __shfl_xor(ssq0, 32, 64);
  ssq1 += __shfl_xor(ssq1, 16, 64); ssq1 += __shfl_xor(ssq1, 32, 64);
  ssq2 += __shfl_xor(ssq2, 16, 64); ssq2 += __shfl_xor(ssq2, 32, 64);
  ssq3 += __shfl_xor(ssq3, 16, 64); ssq3 += __shfl_xor(ssq3, 32, 64);
  if (lane < 16) {
    float4 v; v.x = ssq0; v.y = ssq1; v.z = ssq2; v.w = ssq3;
    *(float4*)&red[wid][sg << 2] = v;
  }
  __syncthreads();
  if (t < 64) {
    float tot = red[0][t] + red[1][t] + red[2][t] + red[3][t];
    invs[t] = 1.0f / fmaxf(sqrtf(tot), EPSF);
  }
  __syncthreads();

  // ---- softmax over k for each s ----
  float li[4];
#pragma unroll
  for (int sgr = 0; sgr < 4; ++sgr) li[sgr] = invs[(sgr << 4) + col];
  float le[4][4];
#pragma unroll
  for (int sgr = 0; sgr < 4; ++sgr)
#pragma unroll
    for (int r = 0; r < 4; ++r) le[sgr][r] = acc[sgr][r] * li[sgr];

  float mx[4];
#pragma unroll
  for (int sgr = 0; sgr < 4; ++sgr) {
    float m = fmaxf(fmaxf(le[sgr][0], le[sgr][1]), fmaxf(le[sgr][2], le[sgr][3]));
    m = fmaxf(m, __shfl_xor(m, 16, 64));
    m = fmaxf(m, __shfl_xor(m, 32, 64));
    mx[sgr] = m;
  }
  if (lane < 16) {
#pragma unroll
    for (int sgr = 0; sgr < 4; ++sgr) red[wid][(sgr << 4) + sg] = mx[sgr];
  }
  __syncthreads();
  if (t < 64)
    gmaxs[t] = fmaxf(fmaxf(red[0][t], red[1][t]), fmaxf(red[2][t], red[3][t]));
  __syncthreads();

  float ps[4];
#pragma unroll
  for (int sgr = 0; sgr < 4; ++sgr) {
    float gm = gmaxs[(sgr << 4) + col];
    float p = 0.f;
#pragma unroll
    for (int r = 0; r < 4; ++r) {
      float e = __expf(le[sgr][r] - gm);
      le[sgr][r] = e;
      p += e;
    }
    p += __shfl_xor(p, 16, 64);
    p += __shfl_xor(p, 32, 64);
    ps[sgr] = p;
  }
  if (lane < 16) {
#pragma unroll
    for (int sgr = 0; sgr < 4; ++sgr) red[wid][(sgr << 4) + sg] = ps[sgr];
  }
  __syncthreads();
  if (t < 64) gsums[t] = red[0][t] + red[1][t] + red[2][t] + red[3][t];
  __syncthreads();

  // ---- a, a' = a*invn, suma ----
  float sk[4] = {0.f, 0.f, 0.f, 0.f};
#pragma unroll
  for (int sgr = 0; sgr < 4; ++sgr) {
    float rinv = 1.0f / gsums[(sgr << 4) + col];
#pragma unroll
    for (int r = 0; r < 4; ++r) {
      float av = le[sgr][r] * rinv;            // a
      sk[r] += av;
      float apv = av * li[sgr];                // a' = a*invn[s]
      int k = (wid << 4) + (quad << 2) + r;
      ap[((size_t)((n << 6) + k) << 10) + s0 + (sgr << 4) + col] =
          (unsigned short)f2bf(apv);
    }
  }
#pragma unroll
  for (int r = 0; r < 4; ++r) {
    sk[r] += __shfl_xor(sk[r], 1, 64);
    sk[r] += __shfl_xor(sk[r], 2, 64);
    sk[r] += __shfl_xor(sk[r], 4, 64);
    sk[r] += __shfl_xor(sk[r], 8, 64);
  }
  if (col == 0) {
#pragma unroll
    for (int r = 0; r < 4; ++r)
      atomicAdd(&suma[(n << 6) + (wid << 4) + (quad << 2) + r], sk[r]);
  }
}

// K3: vlad^T[c,k] = sum_s x[c,s]*a'[k,s]  (bf16 MFMA, x as A, a' as B),
// then - suma[k]*cent[k,c], rnorm2 atomics, LDS-transposed coalesced store.
// x staged as bf16 (A-frag = single ds_read_b128, no per-step cvt);
// lt output buffer aliases the dead tiles (LDS 18 KB total).
__global__ __launch_bounds__(256) void k3_mfma(
    const float* __restrict__ x, const unsigned short* __restrict__ ap,
    const float* __restrict__ cent, const float* __restrict__ suma,
    float* __restrict__ out, float* __restrict__ rnorm2) {
  __shared__ __align__(16) char sm[64 * 72 * 2 * 2];  // 18432 B
  short (*xb)[72] = reinterpret_cast<short(*)[72]>(sm);          // [c][s] bf16
  short (*at)[72] = reinterpret_cast<short(*)[72]>(sm + 9216);   // [k][s] bf16
  float (*lt)[68] = reinterpret_cast<float(*)[68]>(sm);          // [k][c] (epilogue)

  const int n = blockIdx.y;
  const int c0 = blockIdx.x << 6;
  const int t = threadIdx.x;
  const int lane = t & 63;
  const int wid = t >> 6;        // c-band
  const int col = t & 15;
  const int quad = (t >> 4) & 3;
  const int cr = t >> 4;
  const int sg = t & 15;

  f32x4 acc[4] = {{0,0,0,0},{0,0,0,0},{0,0,0,0},{0,0,0,0}};

  for (int s0 = 0; s0 < 1024; s0 += 64) {
#pragma unroll
    for (int p = 0; p < 4; ++p) {
      int c = cr + (p << 4);
      float4 g = *(const float4*)&x[((size_t)((n << 9) + c0 + c) << 10) + s0 + (sg << 2)];
      short4v hx; hx.x = f2bf(g.x); hx.y = f2bf(g.y); hx.z = f2bf(g.z); hx.w = f2bf(g.w);
      *(short4v*)&xb[c][sg << 2] = hx;
      ushort4v a4 = *(const ushort4v*)&ap[((size_t)((n << 6) + c) << 10) + s0 + (sg << 2)];
      *(ushort4v*)&at[c][sg << 2] = a4;
    }
    __syncthreads();
#pragma unroll
    for (int ss = 0; ss < 64; ss += 32) {
      bf16x8 af = *(const bf16x8*)&xb[(wid << 4) + col][ss + (quad << 3)];
#pragma unroll
      for (int kt = 0; kt < 4; ++kt) {
        bf16x8 bfr = *(const bf16x8*)&at[(kt << 4) + col][ss + (quad << 3)];
        acc[kt] = __builtin_amdgcn_mfma_f32_16x16x32_bf16(af, bfr, acc[kt], 0, 0, 0);
      }
    }
    __syncthreads();
  }

  // epilogue: lane holds D[c = wid*16+quad*4+r][k = kt*16+col]
  float sa[4];
#pragma unroll
  for (int kt = 0; kt < 4; ++kt) sa[kt] = suma[(n << 6) + (kt << 4) + col];
  const int crow = (wid << 4) + (quad << 2);
  float r2[4] = {0.f, 0.f, 0.f, 0.f};
#pragma unroll
  for (int kt = 0; kt < 4; ++kt) {
    int k = (kt << 4) + col;
#pragma unroll
    for (int r = 0; r < 4; ++r) {
      int c = crow + r;
      float ce = cent[(k << 9) + c0 + c];
      float val = acc[kt][r] - sa[kt] * ce;
      r2[kt] = fmaf(val, val, r2[kt]);
      lt[k][c] = val;
    }
  }
#pragma unroll
  for (int kt = 0; kt < 4; ++kt) {
    r2[kt] += __shfl_xor(r2[kt], 16, 64);
    r2[kt] += __shfl_xor(r2[kt], 32, 64);
  }
  if (lane < 16) {
#pragma unroll
    for (int kt = 0; kt < 4; ++kt)
      atomicAdd(&rnorm2[(n << 6) + (kt << 4) + sg], r2[kt]);
  }
  __syncthreads();
  // coalesced store of the 64k x 64c tile
#pragma unroll
  for (int u = 0; u < 4; ++u) {
    int k = t >> 2;
    int c = ((t & 3) << 2) + (u << 4);
    float4 v = *(const float4*)&lt[k][c];
    *(float4*)&out[((size_t)((n << 6) + k) << 9) + c0 + c] = v;
  }
}

// K4: fac[n,k] = intra-norm factor * global-norm factor
__global__ __launch_bounds__(64) void k4_factors(const float* __restrict__ rnorm2,
                                                 float* __restrict__ fac) {
  int n = blockIdx.x, k = threadIdx.x;
  float r2 = rnorm2[(n << 6) + k];
  float rn = sqrtf(r2);
  float f = 1.0f / fmaxf(rn, EPSF);
  float nr = rn * f;
  float g = nr * nr;
#pragma unroll
  for (int off = 32; off > 0; off >>= 1) g += __shfl_xor(g, off, 64);
  fac[(n << 6) + k] = f * (1.0f / fmaxf(sqrtf(g), EPSF));
}

// K5: out *= fac  (in place; d_out fully rewritten by K3 each call)
__global__ __launch_bounds__(256) void k5_scale(const float* __restrict__ vlad,
                                                const float* __restrict__ fac,
                                                float* __restrict__ out) {
  int idx = blockIdx.x * 256 + threadIdx.x;  // float4 index
  float4 v = ((const float4*)vlad)[idx];
  float f = fac[idx >> 7];
  float4 o;
  o.x = v.x * f; o.y = v.y * f; o.z = v.z * f; o.w = v.w * f;
  ((float4*)out)[idx] = o;
}

extern "C" void kernel_launch(void* const* d_in, const int* in_sizes, int n_in,
                              void* d_out, int out_size, void* d_ws, size_t ws_size,
                              hipStream_t stream) {
  (void)in_sizes; (void)n_in; (void)out_size; (void)ws_size;
  const float* x = (const float*)d_in[0];     // (64,512,32,32)
  const float* w = (const float*)d_in[1];     // (64,512)
  const float* cent = (const float*)d_in[2];  // (64,512)
  float* out = (float*)d_out;                 // (64, 64*512)

  float* ws = (float*)d_ws;
  float* suma = ws;                                   // 4096
  float* rnorm2 = ws + 4096;                          // 4096
  float* fac = ws + 8192;                             // 4096
  unsigned short* ap = (unsigned short*)(ws + 12288); // 64*64*1024 bf16 = 8 MB

  hipMemsetAsync(ws, 0, 8192 * sizeof(float), stream);  // suma + rnorm2
  k2_mfma<<<dim3(16, 64), 256, 0, stream>>>(x, w, ap, suma);
  k3_mfma<<<dim3(8, 64), 256, 0, stream>>>(x, ap, cent, suma, out, rnorm2);
  k4_factors<<<64, 64, 0, stream>>>(rnorm2, fac);
  k5_scale<<<2048, 256, 0, stream>>>(out, fac, out);
}